// Round 1
// baseline (1863.597 us; speedup 1.0000x reference)
//
#include <hip/hip_runtime.h>
#include <math.h>

#define NCc 16
#define MROWS 400    // N_c*N_S
#define QROWS 240    // N_c*N_Q
#define TOTROWS 640
#define DIN 3072
#define DF 640
#define NMAT 400
#define NB 100
#define NRHS 16
#define CREG 50.0f

// ---------------- GEMM: [S;Q] @ W_base -> K(400x640), FX(240x640) ----------
__global__ __launch_bounds__(256) void gemm_feat(const float* __restrict__ S,
                                                 const float* __restrict__ Qm,
                                                 const float* __restrict__ Wb,
                                                 float* __restrict__ K,
                                                 float* __restrict__ FX) {
  __shared__ float As[16][64];  // [k][row]
  __shared__ float Bs[16][64];  // [k][col]
  int tid = threadIdx.x;
  int bx = blockIdx.x, by = blockIdx.y;
  int ar = tid >> 2, ak = (tid & 3) * 4;
  int arow = by * 64 + ar;  // 0..639, exact (640 = 10*64)
  const float* srcRow = (arow < MROWS) ? (S + (size_t)arow * DIN)
                                       : (Qm + (size_t)(arow - MROWS) * DIN);
  int brow = tid >> 4, bcol = (tid & 15) * 4;
  int tx = tid & 15, ty = tid >> 4;
  float acc[4][4] = {};
  for (int k0 = 0; k0 < DIN; k0 += 16) {
    float4 av = *reinterpret_cast<const float4*>(srcRow + k0 + ak);
    float4 bv = *reinterpret_cast<const float4*>(Wb + (size_t)(k0 + brow) * DF + bx * 64 + bcol);
    __syncthreads();
    As[ak + 0][ar] = av.x; As[ak + 1][ar] = av.y; As[ak + 2][ar] = av.z; As[ak + 3][ar] = av.w;
    Bs[brow][bcol + 0] = bv.x; Bs[brow][bcol + 1] = bv.y; Bs[brow][bcol + 2] = bv.z; Bs[brow][bcol + 3] = bv.w;
    __syncthreads();
#pragma unroll
    for (int kk = 0; kk < 16; ++kk) {
      float a[4], b[4];
#pragma unroll
      for (int i = 0; i < 4; ++i) a[i] = As[kk][ty * 4 + i];
#pragma unroll
      for (int j = 0; j < 4; ++j) b[j] = Bs[kk][tx * 4 + j];
#pragma unroll
      for (int i = 0; i < 4; ++i)
#pragma unroll
        for (int j = 0; j < 4; ++j) acc[i][j] += a[i] * b[j];
    }
  }
#pragma unroll
  for (int i = 0; i < 4; ++i) {
    int row = by * 64 + ty * 4 + i;
    float* dst = (row < MROWS) ? (K + (size_t)row * DF) : (FX + (size_t)(row - MROWS) * DF);
    int col = bx * 64 + tx * 4;
    float4 v = make_float4(acc[i][0], acc[i][1], acc[i][2], acc[i][3]);
    *reinterpret_cast<float4*>(dst + col) = v;
  }
}

// ---------------- aul = K K^T + 50 I  (400x400, full symmetric) ------------
__global__ __launch_bounds__(256) void gemm_aul(const float* __restrict__ K,
                                                float* __restrict__ A) {
  __shared__ float As[16][64];
  __shared__ float Bs[16][64];
  int tid = threadIdx.x;
  int bx = blockIdx.x, by = blockIdx.y;
  int ar = tid >> 2, ak = (tid & 3) * 4;
  int arow = by * 64 + ar;
  int brow = bx * 64 + ar;
  int tx = tid & 15, ty = tid >> 4;
  float acc[4][4] = {};
  for (int k0 = 0; k0 < DF; k0 += 16) {
    float4 av = (arow < MROWS) ? *reinterpret_cast<const float4*>(K + (size_t)arow * DF + k0 + ak)
                               : make_float4(0.f, 0.f, 0.f, 0.f);
    float4 bv = (brow < MROWS) ? *reinterpret_cast<const float4*>(K + (size_t)brow * DF + k0 + ak)
                               : make_float4(0.f, 0.f, 0.f, 0.f);
    __syncthreads();
    As[ak + 0][ar] = av.x; As[ak + 1][ar] = av.y; As[ak + 2][ar] = av.z; As[ak + 3][ar] = av.w;
    Bs[ak + 0][ar] = bv.x; Bs[ak + 1][ar] = bv.y; Bs[ak + 2][ar] = bv.z; Bs[ak + 3][ar] = bv.w;
    __syncthreads();
#pragma unroll
    for (int kk = 0; kk < 16; ++kk) {
      float a[4], b[4];
#pragma unroll
      for (int i = 0; i < 4; ++i) a[i] = As[kk][ty * 4 + i];
#pragma unroll
      for (int j = 0; j < 4; ++j) b[j] = Bs[kk][tx * 4 + j];
#pragma unroll
      for (int i = 0; i < 4; ++i)
#pragma unroll
        for (int j = 0; j < 4; ++j) acc[i][j] += a[i] * b[j];
    }
  }
#pragma unroll
  for (int i = 0; i < 4; ++i) {
#pragma unroll
    for (int j = 0; j < 4; ++j) {
      int row = by * 64 + ty * 4 + i;
      int col = bx * 64 + tx * 4 + j;
      if (row < NMAT && col < NMAT) {
        float v = acc[i][j];
        if (row == col) v += CREG;
        A[(size_t)row * NMAT + col] = v;
      }
    }
  }
}

// packed lower-triangular loader: Lp[tri(i,j)] = A[s+i][s+j], i>=j, NB=100
__device__ __forceinline__ void load_packed_lower(const float* __restrict__ A, int s,
                                                  float* Lp, int tid) {
  for (int e = tid; e < (NB * (NB + 1)) / 2; e += 256) {
    float ef = (float)e;
    int i = (int)((sqrtf(8.f * ef + 1.f) - 1.f) * 0.5f);
    while ((i + 1) * (i + 2) / 2 <= e) ++i;
    while (i * (i + 1) / 2 > e) --i;
    int j = e - (i * (i + 1)) / 2;
    Lp[e] = A[(size_t)(s + i) * NMAT + (s + j)];
  }
}

// ---------------- Cholesky: factor diagonal 100x100 block in LDS -----------
__global__ __launch_bounds__(256) void chol_diag(float* __restrict__ A, int s) {
  __shared__ float T[NB][NB + 1];
  int tid = threadIdx.x;
  for (int e = tid; e < NB * NB; e += 256) {
    int i = e / NB, j = e - (e / NB) * NB;
    T[i][j] = A[(size_t)(s + i) * NMAT + (s + j)];
  }
  __syncthreads();
  for (int k = 0; k < NB; ++k) {
    float d = T[k][k];
    float sq = sqrtf(d);
    float pivinv = 1.f / sq;
    if (tid == 0) T[k][k] = sq;
    for (int i = k + 1 + tid; i < NB; i += 256) T[i][k] *= pivinv;
    __syncthreads();
    int m = NB - 1 - k;
    for (int e = tid; e < m * m; e += 256) {
      int i = k + 1 + e / m;
      int j = k + 1 + (e - (e / m) * m);
      T[i][j] -= T[i][k] * T[j][k];
    }
    __syncthreads();
  }
  for (int e = tid; e < NB * NB; e += 256) {
    int i = e / NB, j = e - (e / NB) * NB;
    A[(size_t)(s + i) * NMAT + (s + j)] = T[i][j];
  }
}

// ---------------- Cholesky: panel solve L21 = A21 * L11^{-T} ---------------
__global__ __launch_bounds__(256) void chol_panel(float* __restrict__ A, int s) {
  __shared__ float Lp[(NB * (NB + 1)) / 2];
  __shared__ float Ap[64 * 102];
  int tid = threadIdx.x;
  int row0 = s + NB + blockIdx.x * 64;
  load_packed_lower(A, s, Lp, tid);
  for (int e = tid; e < 64 * NB; e += 256) {
    int c = e / NB, j = e - (e / NB) * NB;
    int rr = row0 + c;
    Ap[c * 102 + j] = (rr < NMAT) ? A[(size_t)rr * NMAT + s + j] : 0.f;
  }
  __syncthreads();
  for (int j = 0; j < NB; ++j) {
    float pivinv = 1.f / Lp[(j * (j + 1)) / 2 + j];
    if (tid < 64) Ap[tid * 102 + j] *= pivinv;
    __syncthreads();
    int c = tid & 63;
    for (int jj = j + 1 + (tid >> 6); jj < NB; jj += 4) {
      Ap[c * 102 + jj] -= Ap[c * 102 + j] * Lp[(jj * (jj + 1)) / 2 + j];
    }
    __syncthreads();
  }
  for (int e = tid; e < 64 * NB; e += 256) {
    int c = e / NB, j = e - (e / NB) * NB;
    int rr = row0 + c;
    if (rr < NMAT) A[(size_t)rr * NMAT + s + j] = Ap[c * 102 + j];
  }
}

// ---------------- Cholesky: trailing update A22 -= L21 L21^T ---------------
__global__ __launch_bounds__(256) void chol_trail(float* __restrict__ A, int s) {
  __shared__ float La[64 * 102];
  __shared__ float Lb[64 * 102];
  int tid = threadIdx.x;
  int t0 = s + NB;
  int i0 = t0 + blockIdx.y * 64;
  int j0 = t0 + blockIdx.x * 64;
  for (int e = tid; e < 64 * NB; e += 256) {
    int c = e / NB, k = e - (e / NB) * NB;
    int ra = i0 + c, rb = j0 + c;
    La[c * 102 + k] = (ra < NMAT) ? A[(size_t)ra * NMAT + s + k] : 0.f;
    Lb[c * 102 + k] = (rb < NMAT) ? A[(size_t)rb * NMAT + s + k] : 0.f;
  }
  __syncthreads();
  int tx = tid & 15, ty = tid >> 4;
  float acc[4][4] = {};
  for (int k = 0; k < NB; ++k) {
    float a[4], b[4];
#pragma unroll
    for (int i = 0; i < 4; ++i) a[i] = La[(ty * 4 + i) * 102 + k];
#pragma unroll
    for (int j = 0; j < 4; ++j) b[j] = Lb[(tx * 4 + j) * 102 + k];
#pragma unroll
    for (int i = 0; i < 4; ++i)
#pragma unroll
      for (int j = 0; j < 4; ++j) acc[i][j] += a[i] * b[j];
  }
#pragma unroll
  for (int i = 0; i < 4; ++i)
#pragma unroll
    for (int j = 0; j < 4; ++j) {
      int r = i0 + ty * 4 + i;
      int c = j0 + tx * 4 + j;
      if (r < NMAT && c < NMAT) A[(size_t)r * NMAT + c] -= acc[i][j];
    }
}

// ------- single-block blocked forward+backward substitution, 16 RHS --------
__global__ __launch_bounds__(256) void tri_solve(const float* __restrict__ A,
                                                 float* __restrict__ X) {
  __shared__ float Xs[NMAT][NRHS + 1];           // 27.2 KB
  __shared__ float Lp[(NB * (NB + 1)) / 2];      // 20.2 KB
  __shared__ float Lch[3264];                    // 13.1 KB
  int tid = threadIdx.x;
  // init P: P[i][r] = (i/25 == r)
  for (int e = tid; e < NMAT * NRHS; e += 256) {
    int i = e >> 4, r = e & 15;
    Xs[i][r] = ((i / 25) == r) ? 1.f : 0.f;
  }
  __syncthreads();
  // ---- forward: L y = p ----
  for (int p = 0; p < 4; ++p) {
    int s = p * NB;
    load_packed_lower(A, s, Lp, tid);
    __syncthreads();
    for (int j = 0; j < NB; ++j) {
      float pivinv = 1.f / Lp[(j * (j + 1)) / 2 + j];
      if (tid < NRHS) Xs[s + j][tid] *= pivinv;
      __syncthreads();
      int r = tid & 15;
      for (int i = j + 1 + (tid >> 4); i < NB; i += 16) {
        Xs[s + i][r] -= Lp[(i * (i + 1)) / 2 + j] * Xs[s + j][r];
      }
      __syncthreads();
    }
    // rows below panel: Xs[row] -= L[row][s:s+100] . Xs[s:s+100]
    for (int row0 = s + NB; row0 < NMAT; row0 += 32) {
      for (int e = tid; e < 32 * NB; e += 256) {
        int c = e / NB, k = e - (e / NB) * NB;
        int rr = row0 + c;
        Lch[c * 102 + k] = (rr < NMAT) ? A[(size_t)rr * NMAT + s + k] : 0.f;
      }
      __syncthreads();
      for (int e = tid; e < 32 * NRHS; e += 256) {
        int c = e >> 4, r = e & 15;
        int rr = row0 + c;
        if (rr < NMAT) {
          float acc = 0.f;
          for (int k = 0; k < NB; ++k) acc += Lch[c * 102 + k] * Xs[s + k][r];
          Xs[rr][r] -= acc;
        }
      }
      __syncthreads();
    }
  }
  // ---- backward: L^T x = y ----
  for (int p = 3; p >= 0; --p) {
    int s = p * NB;
    load_packed_lower(A, s, Lp, tid);
    __syncthreads();
    for (int j = NB - 1; j >= 0; --j) {
      float pivinv = 1.f / Lp[(j * (j + 1)) / 2 + j];
      if (tid < NRHS) Xs[s + j][tid] *= pivinv;
      __syncthreads();
      int r = tid & 15;
      for (int i = (tid >> 4); i < j; i += 16) {
        Xs[s + i][r] -= Lp[(j * (j + 1)) / 2 + i] * Xs[s + j][r];
      }
      __syncthreads();
    }
    // rows above panel: Xs[i] -= sum_k L[s+k][i] * Xs[s+k]
    for (int i0 = 0; i0 < s; i0 += 32) {
      for (int e = tid; e < 32 * NB; e += 256) {
        int k = e >> 5, c = e & 31;
        Lch[k * 32 + c] = (i0 + c < s) ? A[(size_t)(s + k) * NMAT + i0 + c] : 0.f;
      }
      __syncthreads();
      for (int e = tid; e < 32 * NRHS; e += 256) {
        int c = e >> 4, r = e & 15;
        int ii = i0 + c;
        if (ii < s) {
          float acc = 0.f;
          for (int k = 0; k < NB; ++k) acc += Lch[k * 32 + c] * Xs[s + k][r];
          Xs[ii][r] -= acc;
        }
      }
      __syncthreads();
    }
  }
  for (int e = tid; e < NMAT * NRHS; e += 256) X[e] = Xs[e >> 4][e & 15];
}

// ---------------- w_k = X^T K : WK[j][d] = sum_i X[i][j] K[i][d] -----------
__global__ __launch_bounds__(256) void wk_kernel(const float* __restrict__ X,
                                                 const float* __restrict__ K,
                                                 float* __restrict__ WK) {
  int idx = blockIdx.x * 256 + threadIdx.x;  // < 16*640 = 10240
  int j = idx / DF;
  int d = idx - j * DF;
  float acc = 0.f;
  for (int i = 0; i < NMAT; ++i) acc += X[i * NRHS + j] * K[(size_t)i * DF + d];
  WK[idx] = acc;
}

// ---------------- logits[q][c] = -gamma * dot(FX[q], WK[c]) ----------------
__global__ __launch_bounds__(256) void logits_kernel(const float* __restrict__ FX,
                                                     const float* __restrict__ WK,
                                                     const float* __restrict__ gamma,
                                                     float* __restrict__ out) {
  int idx = blockIdx.x * 256 + threadIdx.x;  // < 240*16 = 3840
  int q = idx >> 4, c = idx & 15;
  const float* fr = FX + (size_t)q * DF;
  const float* wr = WK + (size_t)c * DF;
  float acc = 0.f;
  for (int d = 0; d < DF; ++d) acc += fr[d] * wr[d];
  out[idx] = -gamma[0] * acc;
}

extern "C" void kernel_launch(void* const* d_in, const int* in_sizes, int n_in,
                              void* d_out, int out_size, void* d_ws, size_t ws_size,
                              hipStream_t stream) {
  const float* S = (const float*)d_in[0];      // [400, 3072]
  const float* Qm = (const float*)d_in[1];     // [240, 3072]
  const float* Wb = (const float*)d_in[2];     // [3072, 640]
  const float* gamma = (const float*)d_in[3];  // [1]
  float* out = (float*)d_out;                  // [240, 16]
  float* ws = (float*)d_ws;
  float* K = ws;                   // 400*640 = 256000
  float* FX = ws + 256000;         // 240*640 = 153600
  float* A = ws + 409600;          // 400*400 = 160000
  float* X = ws + 569600;          // 400*16  = 6400
  float* WK = ws + 576000;         // 16*640  = 10240  (total 2.3 MB)

  gemm_feat<<<dim3(10, 10), 256, 0, stream>>>(S, Qm, Wb, K, FX);
  gemm_aul<<<dim3(7, 7), 256, 0, stream>>>(K, A);
  for (int p = 0; p < 4; ++p) {
    int s = p * NB;
    chol_diag<<<1, 256, 0, stream>>>(A, s);
    int r = NMAT - s - NB;
    if (r > 0) {
      int g = (r + 63) / 64;
      chol_panel<<<g, 256, 0, stream>>>(A, s);
      chol_trail<<<dim3(g, g), 256, 0, stream>>>(A, s);
    }
  }
  tri_solve<<<1, 256, 0, stream>>>(A, X);
  wk_kernel<<<40, 256, 0, stream>>>(X, K, WK);
  logits_kernel<<<15, 256, 0, stream>>>(FX, WK, gamma, out);
}

// Round 2
// 865.728 us; speedup vs baseline: 2.1526x; 2.1526x over previous
//
#include <hip/hip_runtime.h>
#include <math.h>

#define MROWS 400    // N_c*N_S
#define QROWS 240    // N_c*N_Q
#define DIN 3072
#define DF 640
#define NMAT 400
#define NRHS 16
#define CREG 50.0f
#define NEWTON_ITERS 10

// ---------------- GEMM: [S;Q] @ W_base -> K(400x640), FX(240x640) ----------
__global__ __launch_bounds__(256) void gemm_feat(const float* __restrict__ S,
                                                 const float* __restrict__ Qm,
                                                 const float* __restrict__ Wb,
                                                 float* __restrict__ K,
                                                 float* __restrict__ FX) {
  __shared__ float As[16][64];  // [k][row]
  __shared__ float Bs[16][64];  // [k][col]
  int tid = threadIdx.x;
  int bx = blockIdx.x, by = blockIdx.y;
  int ar = tid >> 2, ak = (tid & 3) * 4;
  int arow = by * 64 + ar;  // 0..639, exact (640 = 10*64)
  const float* srcRow = (arow < MROWS) ? (S + (size_t)arow * DIN)
                                       : (Qm + (size_t)(arow - MROWS) * DIN);
  int brow = tid >> 4, bcol = (tid & 15) * 4;
  int tx = tid & 15, ty = tid >> 4;
  float acc[4][4] = {};
  for (int k0 = 0; k0 < DIN; k0 += 16) {
    float4 av = *reinterpret_cast<const float4*>(srcRow + k0 + ak);
    float4 bv = *reinterpret_cast<const float4*>(Wb + (size_t)(k0 + brow) * DF + bx * 64 + bcol);
    __syncthreads();
    As[ak + 0][ar] = av.x; As[ak + 1][ar] = av.y; As[ak + 2][ar] = av.z; As[ak + 3][ar] = av.w;
    Bs[brow][bcol + 0] = bv.x; Bs[brow][bcol + 1] = bv.y; Bs[brow][bcol + 2] = bv.z; Bs[brow][bcol + 3] = bv.w;
    __syncthreads();
#pragma unroll
    for (int kk = 0; kk < 16; ++kk) {
      float a[4], b[4];
#pragma unroll
      for (int i = 0; i < 4; ++i) a[i] = As[kk][ty * 4 + i];
#pragma unroll
      for (int j = 0; j < 4; ++j) b[j] = Bs[kk][tx * 4 + j];
#pragma unroll
      for (int i = 0; i < 4; ++i)
#pragma unroll
        for (int j = 0; j < 4; ++j) acc[i][j] += a[i] * b[j];
    }
  }
#pragma unroll
  for (int i = 0; i < 4; ++i) {
    int row = by * 64 + ty * 4 + i;
    float* dst = (row < MROWS) ? (K + (size_t)row * DF) : (FX + (size_t)(row - MROWS) * DF);
    int col = bx * 64 + tx * 4;
    float4 v = make_float4(acc[i][0], acc[i][1], acc[i][2], acc[i][3]);
    *reinterpret_cast<float4*>(dst + col) = v;
  }
}

// ---------------- aul = K K^T + 50 I  (400x400, full symmetric) ------------
__global__ __launch_bounds__(256) void gemm_aul(const float* __restrict__ K,
                                                float* __restrict__ A) {
  __shared__ float As[16][64];
  __shared__ float Bs[16][64];
  int tid = threadIdx.x;
  int bx = blockIdx.x, by = blockIdx.y;
  int ar = tid >> 2, ak = (tid & 3) * 4;
  int arow = by * 64 + ar;
  int brow = bx * 64 + ar;
  int tx = tid & 15, ty = tid >> 4;
  float acc[4][4] = {};
  for (int k0 = 0; k0 < DF; k0 += 16) {
    float4 av = (arow < MROWS) ? *reinterpret_cast<const float4*>(K + (size_t)arow * DF + k0 + ak)
                               : make_float4(0.f, 0.f, 0.f, 0.f);
    float4 bv = (brow < MROWS) ? *reinterpret_cast<const float4*>(K + (size_t)brow * DF + k0 + ak)
                               : make_float4(0.f, 0.f, 0.f, 0.f);
    __syncthreads();
    As[ak + 0][ar] = av.x; As[ak + 1][ar] = av.y; As[ak + 2][ar] = av.z; As[ak + 3][ar] = av.w;
    Bs[ak + 0][ar] = bv.x; Bs[ak + 1][ar] = bv.y; Bs[ak + 2][ar] = bv.z; Bs[ak + 3][ar] = bv.w;
    __syncthreads();
#pragma unroll
    for (int kk = 0; kk < 16; ++kk) {
      float a[4], b[4];
#pragma unroll
      for (int i = 0; i < 4; ++i) a[i] = As[kk][ty * 4 + i];
#pragma unroll
      for (int j = 0; j < 4; ++j) b[j] = Bs[kk][tx * 4 + j];
#pragma unroll
      for (int i = 0; i < 4; ++i)
#pragma unroll
        for (int j = 0; j < 4; ++j) acc[i][j] += a[i] * b[j];
    }
  }
#pragma unroll
  for (int i = 0; i < 4; ++i) {
#pragma unroll
    for (int j = 0; j < 4; ++j) {
      int row = by * 64 + ty * 4 + i;
      int col = bx * 64 + tx * 4 + j;
      if (row < NMAT && col < NMAT) {
        float v = acc[i][j];
        if (row == col) v += CREG;
        A[(size_t)row * NMAT + col] = v;
      }
    }
  }
}

// -------- Gershgorin bound: cbuf[0] = 2/(50 + max_i sum_j |A[i][j]|) -------
// lambda_min(aul) >= 50 provably (KK^T PSD); lambda_max <= max abs row sum.
__global__ __launch_bounds__(256) void gersh_kernel(const float* __restrict__ A,
                                                    float* __restrict__ cbuf) {
  __shared__ float red[256];
  int tid = threadIdx.x;
  float m = 0.f;
  for (int i = tid; i < NMAT; i += 256) {
    const float* ar = A + (size_t)i * NMAT;
    float s = 0.f;
    for (int j = 0; j < NMAT; ++j) s += fabsf(ar[j]);
    m = fmaxf(m, s);
  }
  red[tid] = m;
  __syncthreads();
  for (int o = 128; o > 0; o >>= 1) {
    if (tid < o) red[tid] = fmaxf(red[tid], red[tid + o]);
    __syncthreads();
  }
  if (tid == 0) cbuf[0] = 2.f / (CREG + red[0]);
}

// ---------------- Y0 = c * I ----------------
__global__ __launch_bounds__(256) void inity_kernel(const float* __restrict__ cbuf,
                                                    float* __restrict__ Y) {
  int idx = blockIdx.x * 256 + threadIdx.x;
  if (idx < NMAT * NMAT) {
    int i = idx / NMAT, j = idx - i * NMAT;
    Y[idx] = (i == j) ? cbuf[0] : 0.f;
  }
}

// ------- C = A@B (mode 0) or C = 2*A - A@B (mode 1); all 400x400 -----------
__global__ __launch_bounds__(256) void gemm400(const float* __restrict__ A,
                                               const float* __restrict__ B,
                                               float* __restrict__ C, int mode) {
  __shared__ float As[16][64];
  __shared__ float Bs[16][64];
  int tid = threadIdx.x;
  int bx = blockIdx.x, by = blockIdx.y;
  int ar = tid >> 2, ak = (tid & 3) * 4;
  int arow = by * 64 + ar;
  int brow = tid >> 4, bcol = (tid & 15) * 4;
  int bc = bx * 64 + bcol;
  int tx = tid & 15, ty = tid >> 4;
  float acc[4][4] = {};
  for (int k0 = 0; k0 < NMAT; k0 += 16) {  // 400 = 25*16 exact
    float4 av = (arow < NMAT) ? *reinterpret_cast<const float4*>(A + (size_t)arow * NMAT + k0 + ak)
                              : make_float4(0.f, 0.f, 0.f, 0.f);
    float4 bv = (bc < NMAT) ? *reinterpret_cast<const float4*>(B + (size_t)(k0 + brow) * NMAT + bc)
                            : make_float4(0.f, 0.f, 0.f, 0.f);
    __syncthreads();
    As[ak + 0][ar] = av.x; As[ak + 1][ar] = av.y; As[ak + 2][ar] = av.z; As[ak + 3][ar] = av.w;
    Bs[brow][bcol + 0] = bv.x; Bs[brow][bcol + 1] = bv.y; Bs[brow][bcol + 2] = bv.z; Bs[brow][bcol + 3] = bv.w;
    __syncthreads();
#pragma unroll
    for (int kk = 0; kk < 16; ++kk) {
      float a[4], b[4];
#pragma unroll
      for (int i = 0; i < 4; ++i) a[i] = As[kk][ty * 4 + i];
#pragma unroll
      for (int j = 0; j < 4; ++j) b[j] = Bs[kk][tx * 4 + j];
#pragma unroll
      for (int i = 0; i < 4; ++i)
#pragma unroll
        for (int j = 0; j < 4; ++j) acc[i][j] += a[i] * b[j];
    }
  }
#pragma unroll
  for (int i = 0; i < 4; ++i) {
    int row = by * 64 + ty * 4 + i;
    int col = bx * 64 + tx * 4;
    if (row < NMAT && col < NMAT) {  // col multiple of 4, 400%4==0 -> float4 safe
      float4 v;
      if (mode == 1) {
        float4 ya = *reinterpret_cast<const float4*>(A + (size_t)row * NMAT + col);
        v = make_float4(2.f * ya.x - acc[i][0], 2.f * ya.y - acc[i][1],
                        2.f * ya.z - acc[i][2], 2.f * ya.w - acc[i][3]);
      } else {
        v = make_float4(acc[i][0], acc[i][1], acc[i][2], acc[i][3]);
      }
      *reinterpret_cast<float4*>(C + (size_t)row * NMAT + col) = v;
    }
  }
}

// ---- X1 = Y @ P : P[j][c] = (j/25==c)  ->  X1[i][c] = sum_{j in seg c} Y[i][j]
__global__ __launch_bounds__(256) void yp_kernel(const float* __restrict__ Y,
                                                 float* __restrict__ X1) {
  int idx = blockIdx.x * 256 + threadIdx.x;  // 400*16 = 6400
  if (idx >= NMAT * NRHS) return;
  int i = idx >> 4, c = idx & 15;
  const float* yr = Y + (size_t)i * NMAT + c * 25;
  float s = 0.f;
#pragma unroll
  for (int j = 0; j < 25; ++j) s += yr[j];
  X1[idx] = s;
}

// ---- R = P - A @ X1 ----
__global__ __launch_bounds__(256) void resid_kernel(const float* __restrict__ A,
                                                    const float* __restrict__ X1,
                                                    float* __restrict__ R) {
  int idx = blockIdx.x * 256 + threadIdx.x;
  if (idx >= NMAT * NRHS) return;
  int i = idx >> 4, c = idx & 15;
  const float* ar = A + (size_t)i * NMAT;
  float s = ((i / 25) == c) ? 1.f : 0.f;
  for (int j = 0; j < NMAT; ++j) s -= ar[j] * X1[j * NRHS + c];
  R[idx] = s;
}

// ---- X = X1 + Y @ R ----
__global__ __launch_bounds__(256) void update_kernel(const float* __restrict__ Y,
                                                     const float* __restrict__ X1,
                                                     const float* __restrict__ R,
                                                     float* __restrict__ X) {
  int idx = blockIdx.x * 256 + threadIdx.x;
  if (idx >= NMAT * NRHS) return;
  int i = idx >> 4, c = idx & 15;
  const float* yr = Y + (size_t)i * NMAT;
  float s = X1[idx];
  for (int j = 0; j < NMAT; ++j) s += yr[j] * R[j * NRHS + c];
  X[idx] = s;
}

// ---------------- w_k = X^T K : WK[j][d] = sum_i X[i][j] K[i][d] -----------
__global__ __launch_bounds__(256) void wk_kernel(const float* __restrict__ X,
                                                 const float* __restrict__ K,
                                                 float* __restrict__ WK) {
  int idx = blockIdx.x * 256 + threadIdx.x;  // < 16*640 = 10240
  int j = idx / DF;
  int d = idx - j * DF;
  float acc = 0.f;
  for (int i = 0; i < NMAT; ++i) acc += X[i * NRHS + j] * K[(size_t)i * DF + d];
  WK[idx] = acc;
}

// ---------------- logits[q][c] = -gamma * dot(FX[q], WK[c]) ----------------
__global__ __launch_bounds__(256) void logits_kernel(const float* __restrict__ FX,
                                                     const float* __restrict__ WK,
                                                     const float* __restrict__ gamma,
                                                     float* __restrict__ out) {
  int idx = blockIdx.x * 256 + threadIdx.x;  // < 240*16 = 3840
  int q = idx >> 4, c = idx & 15;
  const float* fr = FX + (size_t)q * DF;
  const float* wr = WK + (size_t)c * DF;
  float acc = 0.f;
  for (int d = 0; d < DF; ++d) acc += fr[d] * wr[d];
  out[idx] = -gamma[0] * acc;
}

extern "C" void kernel_launch(void* const* d_in, const int* in_sizes, int n_in,
                              void* d_out, int out_size, void* d_ws, size_t ws_size,
                              hipStream_t stream) {
  const float* S = (const float*)d_in[0];      // [400, 3072]
  const float* Qm = (const float*)d_in[1];     // [240, 3072]
  const float* Wb = (const float*)d_in[2];     // [3072, 640]
  const float* gamma = (const float*)d_in[3];  // [1]
  float* out = (float*)d_out;                  // [240, 16]
  float* ws = (float*)d_ws;
  float* K   = ws;                 // 400*640 = 256000
  float* FX  = ws + 256000;        // 240*640 = 153600
  float* A   = ws + 409600;        // 400*400 = 160000
  float* Ya  = ws + 569600;        // 160000
  float* Yb  = ws + 729600;        // 160000
  float* T   = ws + 889600;        // 160000
  float* X1  = ws + 1049600;       // 6400
  float* R   = ws + 1056000;       // 6400
  float* X   = ws + 1062400;       // 6400
  float* WK  = ws + 1068800;       // 10240
  float* cbuf= ws + 1079040;       // 1        (total ~4.32 MB)

  gemm_feat<<<dim3(10, 10), 256, 0, stream>>>(S, Qm, Wb, K, FX);
  gemm_aul<<<dim3(7, 7), 256, 0, stream>>>(K, A);
  gersh_kernel<<<1, 256, 0, stream>>>(A, cbuf);
  inity_kernel<<<625, 256, 0, stream>>>(cbuf, Ya);
  // Newton-Schulz: Y <- 2Y - Y(AY); E=I-YA squares each iter, rho0<=(b-50)/(b+50)
  for (int it = 0; it < NEWTON_ITERS; ++it) {
    gemm400<<<dim3(7, 7), 256, 0, stream>>>(A, Ya, T, 0);    // T  = A @ Ya
    gemm400<<<dim3(7, 7), 256, 0, stream>>>(Ya, T, Yb, 1);   // Yb = 2Ya - Ya @ T
    float* tmp = Ya; Ya = Yb; Yb = tmp;
  }
  // X1 = Ya@P; one refinement step: X = X1 + Ya(P - A X1)  (squares residual op)
  yp_kernel<<<25, 256, 0, stream>>>(Ya, X1);
  resid_kernel<<<25, 256, 0, stream>>>(A, X1, R);
  update_kernel<<<25, 256, 0, stream>>>(Ya, X1, R, X);
  wk_kernel<<<40, 256, 0, stream>>>(X, K, WK);
  logits_kernel<<<15, 256, 0, stream>>>(FX, WK, gamma, out);
}

// Round 3
// 681.122 us; speedup vs baseline: 2.7361x; 1.2710x over previous
//
#include <hip/hip_runtime.h>
#include <math.h>

#define DIN 3072
#define DF 640
#define TOT 640
#define MROWS 400
#define QROWS 240
#define NMAT 400
#define PN 416          // padded Newton dim (13*32, 26*16)
#define NRHS 16
#define CREG 50.0f
#define NEWTON_ITERS 9

typedef __attribute__((ext_vector_type(8))) short bf8v;   // 8 bf16 (4 VGPRs)
typedef __attribute__((ext_vector_type(4))) float f32x4;  // MFMA acc

__device__ __forceinline__ short bf16_rn(float x) {
  unsigned u = __float_as_uint(x);
  u += 0x7FFFu + ((u >> 16) & 1u);
  return (short)(u >> 16);
}
__device__ __forceinline__ void split_sh(float x, short& h, short& l) {
  h = bf16_rn(x);
  float hf = __uint_as_float(((unsigned)(unsigned short)h) << 16);
  l = bf16_rn(x - hf);
}

// ---- transpose + split Wb(3072x640) -> Wth,Wtl [640][3072] bf16 ----------
__global__ __launch_bounds__(256) void split_wt(const float* __restrict__ Wb,
                                                short* __restrict__ H,
                                                short* __restrict__ L) {
  __shared__ float T[64][65];
  int n0 = blockIdx.x * 64;   // over DF
  int k0 = blockIdx.y * 64;   // over DIN
  int c = threadIdx.x & 63, r0 = threadIdx.x >> 6;
#pragma unroll
  for (int i = 0; i < 16; ++i) {
    int r = i * 4 + r0;
    T[r][c] = Wb[(size_t)(k0 + r) * DF + n0 + c];
  }
  __syncthreads();
#pragma unroll
  for (int i = 0; i < 16; ++i) {
    int n = i * 4 + r0;
    float x = T[c][n];              // Wb[k0+c][n0+n]
    short h, l; split_sh(x, h, l);
    size_t o = (size_t)(n0 + n) * DIN + k0 + c;
    H[o] = h; L[o] = l;
  }
}

// ---- MFMA GEMM: [S;Q](640x3072) @ Wb -> Kf(400x640), FX(240x640) + K split
__global__ __launch_bounds__(256) void gemm_feat(const float* __restrict__ S,
                                                 const float* __restrict__ Qm,
                                                 const short* __restrict__ Bh,
                                                 const short* __restrict__ Bl,
                                                 float* __restrict__ Kf,
                                                 float* __restrict__ FX,
                                                 short* __restrict__ Kh,
                                                 short* __restrict__ Kl) {
  int tid = threadIdx.x;
  int wave = tid >> 6, lane = tid & 63;
  int l16 = lane & 15, quad = lane >> 4;
  int row0 = blockIdx.y * 64 + wave * 16;
  int colBase = blockIdx.x * 64;
  int arow = row0 + l16;
  const float* srow = (arow < MROWS) ? (S + (size_t)arow * DIN)
                                     : (Qm + (size_t)(arow - MROWS) * DIN);
  f32x4 acc[4] = {{0,0,0,0},{0,0,0,0},{0,0,0,0},{0,0,0,0}};
  for (int k0 = 0; k0 < DIN; k0 += 32) {
    int ka = k0 + quad * 8;
    float4 v0 = *reinterpret_cast<const float4*>(srow + ka);
    float4 v1 = *reinterpret_cast<const float4*>(srow + ka + 4);
    bf8v ah, al;
    float av[8] = {v0.x, v0.y, v0.z, v0.w, v1.x, v1.y, v1.z, v1.w};
#pragma unroll
    for (int j = 0; j < 8; ++j) { short h, l; split_sh(av[j], h, l); ah[j] = h; al[j] = l; }
#pragma unroll
    for (int t = 0; t < 4; ++t) {
      size_t bo = (size_t)(colBase + t * 16 + l16) * DIN + ka;
      bf8v bh = *reinterpret_cast<const bf8v*>(Bh + bo);
      bf8v bl = *reinterpret_cast<const bf8v*>(Bl + bo);
      acc[t] = __builtin_amdgcn_mfma_f32_16x16x32_bf16(ah, bh, acc[t], 0, 0, 0);
      acc[t] = __builtin_amdgcn_mfma_f32_16x16x32_bf16(ah, bl, acc[t], 0, 0, 0);
      acc[t] = __builtin_amdgcn_mfma_f32_16x16x32_bf16(al, bh, acc[t], 0, 0, 0);
    }
  }
#pragma unroll
  for (int t = 0; t < 4; ++t) {
#pragma unroll
    for (int r = 0; r < 4; ++r) {
      int row = row0 + quad * 4 + r;
      int col = colBase + t * 16 + l16;
      float v = acc[t][r];
      if (row < MROWS) {
        Kf[(size_t)row * DF + col] = v;
        short h, l; split_sh(v, h, l);
        Kh[(size_t)row * DF + col] = h;
        Kl[(size_t)row * DF + col] = l;
      } else {
        FX[(size_t)(row - MROWS) * DF + col] = v;
      }
    }
  }
}

// ---- MFMA: Apad(416x416) = K K^T + 50 I (zero-padded) + bf16 split --------
__global__ __launch_bounds__(256) void gemm_aul(const short* __restrict__ Kh,
                                                const short* __restrict__ Kl,
                                                float* __restrict__ Apad,
                                                short* __restrict__ Aph,
                                                short* __restrict__ Apl) {
  int tid = threadIdx.x;
  int wave = tid >> 6, lane = tid & 63;
  int l16 = lane & 15, quad = lane >> 4;
  int row0 = blockIdx.y * 64 + wave * 16;
  int colBase = blockIdx.x * 64;
  bool aValid = (row0 < MROWS);
  const bf8v bzero = {0,0,0,0,0,0,0,0};
  f32x4 acc[4] = {{0,0,0,0},{0,0,0,0},{0,0,0,0},{0,0,0,0}};
  for (int k0 = 0; k0 < DF; k0 += 32) {
    int ka = k0 + quad * 8;
    bf8v ah = bzero, al = bzero;
    if (aValid) {
      size_t ao = (size_t)(row0 + l16) * DF + ka;
      ah = *reinterpret_cast<const bf8v*>(Kh + ao);
      al = *reinterpret_cast<const bf8v*>(Kl + ao);
    }
#pragma unroll
    for (int t = 0; t < 4; ++t) {
      int colt = colBase + t * 16;
      bf8v bh = bzero, bl = bzero;
      if (colt < MROWS) {
        size_t bo = (size_t)(colt + l16) * DF + ka;
        bh = *reinterpret_cast<const bf8v*>(Kh + bo);
        bl = *reinterpret_cast<const bf8v*>(Kl + bo);
      }
      acc[t] = __builtin_amdgcn_mfma_f32_16x16x32_bf16(ah, bh, acc[t], 0, 0, 0);
      acc[t] = __builtin_amdgcn_mfma_f32_16x16x32_bf16(ah, bl, acc[t], 0, 0, 0);
      acc[t] = __builtin_amdgcn_mfma_f32_16x16x32_bf16(al, bh, acc[t], 0, 0, 0);
    }
  }
  if (row0 >= PN) return;
#pragma unroll
  for (int t = 0; t < 4; ++t) {
    int colt = colBase + t * 16;
    if (colt >= PN) continue;
#pragma unroll
    for (int r = 0; r < 4; ++r) {
      int row = row0 + quad * 4 + r;
      int col = colt + l16;
      float v = acc[t][r];
      if (row == col && row < MROWS) v += CREG;
      size_t o = (size_t)row * PN + col;
      Apad[o] = v;
      short h, l; split_sh(v, h, l);
      Aph[o] = h; Apl[o] = l;
    }
  }
}

// ---- Gershgorin: cbuf[0] = 2/(50 + max_i sum_j |A[i][j]|) -----------------
__global__ __launch_bounds__(256) void gersh_kernel(const float* __restrict__ A,
                                                    float* __restrict__ cbuf) {
  __shared__ float red[256];
  int tid = threadIdx.x;
  float m = 0.f;
  for (int i = tid; i < PN; i += 256) {
    const float* ar = A + (size_t)i * PN;
    float s = 0.f;
    for (int j = 0; j < PN; j += 4) {
      float4 v = *reinterpret_cast<const float4*>(ar + j);
      s += fabsf(v.x) + fabsf(v.y) + fabsf(v.z) + fabsf(v.w);
    }
    m = fmaxf(m, s);
  }
  red[tid] = m;
  __syncthreads();
  for (int o = 128; o > 0; o >>= 1) {
    if (tid < o) red[tid] = fmaxf(red[tid], red[tid + o]);
    __syncthreads();
  }
  if (tid == 0) cbuf[0] = 2.f / (CREG + red[0]);
}

// ---- Y0 = c*I (padded, zero pad-diag) + split -----------------------------
__global__ __launch_bounds__(256) void inity_kernel(const float* __restrict__ cbuf,
                                                    float* __restrict__ Y,
                                                    short* __restrict__ Yh,
                                                    short* __restrict__ Yl) {
  int idx = blockIdx.x * 256 + threadIdx.x;
  if (idx >= PN * PN) return;
  int i = idx / PN, j = idx - i * PN;
  float v = (i == j && i < NMAT) ? cbuf[0] : 0.f;
  Y[idx] = v;
  short h, l; split_sh(v, h, l);
  Yh[idx] = h; Yl[idx] = l;
}

// ---- Newton GEMM on 416: mode0: C = A@B ; mode1: C = 2W - A@B -------------
// B given row-major but used as B-operand via symmetry (B symmetric).
__global__ __launch_bounds__(256) void gemm_nt(const short* __restrict__ Ah,
                                               const short* __restrict__ Al,
                                               const short* __restrict__ Bh,
                                               const short* __restrict__ Bl,
                                               const float* __restrict__ W,
                                               float* __restrict__ Cf,
                                               short* __restrict__ Ch,
                                               short* __restrict__ Cl,
                                               int mode) {
  int tid = threadIdx.x;
  int wave = tid >> 6, lane = tid & 63;
  int l16 = lane & 15, quad = lane >> 4;
  int row0 = blockIdx.y * 64 + wave * 16;
  int colBase = blockIdx.x * 64;
  bool aValid = (row0 < PN);
  const bf8v bzero = {0,0,0,0,0,0,0,0};
  f32x4 acc[4] = {{0,0,0,0},{0,0,0,0},{0,0,0,0},{0,0,0,0}};
  for (int k0 = 0; k0 < PN; k0 += 32) {
    int ka = k0 + quad * 8;
    bf8v ah = bzero, al = bzero;
    if (aValid) {
      size_t ao = (size_t)(row0 + l16) * PN + ka;
      ah = *reinterpret_cast<const bf8v*>(Ah + ao);
      al = *reinterpret_cast<const bf8v*>(Al + ao);
    }
#pragma unroll
    for (int t = 0; t < 4; ++t) {
      int colt = colBase + t * 16;
      bf8v bh = bzero, bl = bzero;
      if (colt < PN) {
        size_t bo = (size_t)(colt + l16) * PN + ka;   // B[k][n]=B[n][k] (sym)
        bh = *reinterpret_cast<const bf8v*>(Bh + bo);
        bl = *reinterpret_cast<const bf8v*>(Bl + bo);
      }
      acc[t] = __builtin_amdgcn_mfma_f32_16x16x32_bf16(ah, bh, acc[t], 0, 0, 0);
      acc[t] = __builtin_amdgcn_mfma_f32_16x16x32_bf16(ah, bl, acc[t], 0, 0, 0);
      acc[t] = __builtin_amdgcn_mfma_f32_16x16x32_bf16(al, bh, acc[t], 0, 0, 0);
    }
  }
  if (row0 >= PN) return;
#pragma unroll
  for (int t = 0; t < 4; ++t) {
    int colt = colBase + t * 16;
    if (colt >= PN) continue;
#pragma unroll
    for (int r = 0; r < 4; ++r) {
      int row = row0 + quad * 4 + r;
      int col = colt + l16;
      size_t o = (size_t)row * PN + col;
      float v = acc[t][r];
      if (mode == 1) v = 2.f * W[o] - v;
      if (mode == 1) Cf[o] = v;
      short h, l; split_sh(v, h, l);
      Ch[o] = h; Cl[o] = l;
    }
  }
}

// ---- X1 = Y @ P (P indicator): row-segment sums ---------------------------
__global__ __launch_bounds__(256) void yp_kernel(const float* __restrict__ Y,
                                                 float* __restrict__ X1) {
  int idx = blockIdx.x * 256 + threadIdx.x;
  if (idx >= NMAT * NRHS) return;
  int i = idx >> 4, c = idx & 15;
  const float* yr = Y + (size_t)i * PN + c * 25;
  float s = 0.f;
#pragma unroll
  for (int j = 0; j < 25; ++j) s += yr[j];
  X1[idx] = s;
}

// ---- R = P - A @ X1 -------------------------------------------------------
__global__ __launch_bounds__(256) void resid_kernel(const float* __restrict__ A,
                                                    const float* __restrict__ X1,
                                                    float* __restrict__ R) {
  int idx = blockIdx.x * 256 + threadIdx.x;
  if (idx >= NMAT * NRHS) return;
  int i = idx >> 4, c = idx & 15;
  const float* ar = A + (size_t)i * PN;
  float s = ((i / 25) == c) ? 1.f : 0.f;
  for (int j = 0; j < NMAT; ++j) s -= ar[j] * X1[j * NRHS + c];
  R[idx] = s;
}

// ---- X = X1 + Y @ R -------------------------------------------------------
__global__ __launch_bounds__(256) void update_kernel(const float* __restrict__ Y,
                                                     const float* __restrict__ X1,
                                                     const float* __restrict__ R,
                                                     float* __restrict__ X) {
  int idx = blockIdx.x * 256 + threadIdx.x;
  if (idx >= NMAT * NRHS) return;
  int i = idx >> 4, c = idx & 15;
  const float* yr = Y + (size_t)i * PN;
  float s = X1[idx];
  for (int j = 0; j < NMAT; ++j) s += yr[j] * R[j * NRHS + c];
  X[idx] = s;
}

// ---- WK[j][d] = sum_i X[i][j] K[i][d] -------------------------------------
__global__ __launch_bounds__(256) void wk_kernel(const float* __restrict__ X,
                                                 const float* __restrict__ K,
                                                 float* __restrict__ WK) {
  int idx = blockIdx.x * 256 + threadIdx.x;
  int j = idx / DF;
  int d = idx - j * DF;
  float acc = 0.f;
  for (int i = 0; i < NMAT; ++i) acc += X[i * NRHS + j] * K[(size_t)i * DF + d];
  WK[idx] = acc;
}

// ---- logits[q][c] = -gamma * dot(FX[q], WK[c]) ----------------------------
__global__ __launch_bounds__(256) void logits_kernel(const float* __restrict__ FX,
                                                     const float* __restrict__ WK,
                                                     const float* __restrict__ gamma,
                                                     float* __restrict__ out) {
  int idx = blockIdx.x * 256 + threadIdx.x;
  int q = idx >> 4, c = idx & 15;
  const float* fr = FX + (size_t)q * DF;
  const float* wr = WK + (size_t)c * DF;
  float acc = 0.f;
  for (int d = 0; d < DF; ++d) acc += fr[d] * wr[d];
  out[idx] = -gamma[0] * acc;
}

extern "C" void kernel_launch(void* const* d_in, const int* in_sizes, int n_in,
                              void* d_out, int out_size, void* d_ws, size_t ws_size,
                              hipStream_t stream) {
  const float* S = (const float*)d_in[0];
  const float* Qm = (const float*)d_in[1];
  const float* Wb = (const float*)d_in[2];
  const float* gamma = (const float*)d_in[3];
  float* out = (float*)d_out;
  char* base = (char*)d_ws;
  // persistent region (~2.78 MB)
  float* Kf  = (float*)(base);                 // 400*640*4   = 1,024,000
  float* FX  = (float*)(base + 1024000);       // 240*640*4   =   614,400
  short* Kh  = (short*)(base + 1638400);       // 400*640*2   =   512,000
  short* Kl  = (short*)(base + 2150400);       //             =   512,000
  float* WK  = (float*)(base + 2662400);       // 16*640*4    =    40,960
  float* X1  = (float*)(base + 2703360);       // 6400*4
  float* Rr  = (float*)(base + 2728960);
  float* Xs  = (float*)(base + 2754560);
  float* cbuf= (float*)(base + 2780160);
  char* big = base + 2780192;
  // phase 1: Wb transposed splits (dead after gemm_feat)
  short* Wth = (short*)(big);                  // 640*3072*2 = 3,932,160
  short* Wtl = (short*)(big + 3932160);
  // phase 2: Newton buffers (alias onto phase-1 region)
  float* Apad= (float*)(big);                  // 416*416*4 = 692,224
  short* Aph = (short*)(big +  692224);        // 346,112
  short* Apl = (short*)(big + 1038336);
  float* Ya  = (float*)(big + 1384448);
  float* Yb  = (float*)(big + 2076672);
  short* Yah = (short*)(big + 2768896);
  short* Yal = (short*)(big + 3115008);
  short* Ybh = (short*)(big + 3461120);
  short* Ybl = (short*)(big + 3807232);
  short* Uh  = (short*)(big + 4153344);
  short* Ul  = (short*)(big + 4499456);        // end big + 4,845,568 (~10.6 MB total)

  split_wt<<<dim3(10, 48), 256, 0, stream>>>(Wb, Wth, Wtl);
  gemm_feat<<<dim3(10, 10), 256, 0, stream>>>(S, Qm, Wth, Wtl, Kf, FX, Kh, Kl);
  gemm_aul<<<dim3(7, 7), 256, 0, stream>>>(Kh, Kl, Apad, Aph, Apl);
  gersh_kernel<<<1, 256, 0, stream>>>(Apad, cbuf);
  inity_kernel<<<676, 256, 0, stream>>>(cbuf, Ya, Yah, Yal);
  float* ya = Ya; short *yah = Yah, *yal = Yal;
  float* yb = Yb; short *ybh = Ybh, *ybl = Ybl;
  for (int it = 0; it < NEWTON_ITERS; ++it) {
    // U = Ya @ A   (B-operand = A, symmetric)
    gemm_nt<<<dim3(7, 7), 256, 0, stream>>>(yah, yal, Aph, Apl, (const float*)0,
                                            (float*)0, Uh, Ul, 0);
    // Yb = 2*Ya - U @ Ya  (B-operand = Ya, symmetric)
    gemm_nt<<<dim3(7, 7), 256, 0, stream>>>(Uh, Ul, yah, yal, ya, yb, ybh, ybl, 1);
    float* tf = ya; ya = yb; yb = tf;
    short* t1 = yah; yah = ybh; ybh = t1;
    short* t2 = yal; yal = ybl; ybl = t2;
  }
  yp_kernel<<<25, 256, 0, stream>>>(ya, X1);
  resid_kernel<<<25, 256, 0, stream>>>(Apad, X1, Rr);
  update_kernel<<<25, 256, 0, stream>>>(ya, X1, Rr, Xs);
  wk_kernel<<<40, 256, 0, stream>>>(Xs, Kf, WK);
  logits_kernel<<<15, 256, 0, stream>>>(FX, WK, gamma, out);
}

// Round 4
// 621.654 us; speedup vs baseline: 2.9978x; 1.0957x over previous
//
#include <hip/hip_runtime.h>
#include <math.h>

#define DIN 3072
#define DF 640
#define MROWS 400
#define QROWS 240
#define NMAT 400
#define PN 416          // padded A dim (13*32)
#define NRHS 16
#define CREG 50.0f
#define NSTEPS 32       // Chebyshev steps: rate~0.78 -> rel ~7e-4
#define PVSTEPS 8

typedef __attribute__((ext_vector_type(8))) short bf8v;   // 8 bf16 (4 VGPRs)
typedef __attribute__((ext_vector_type(4))) float f32x4;  // MFMA acc

__device__ __forceinline__ short bf16_rn(float x) {
  unsigned u = __float_as_uint(x);
  u += 0x7FFFu + ((u >> 16) & 1u);
  return (short)(u >> 16);
}
__device__ __forceinline__ void split_sh(float x, short& h, short& l) {
  h = bf16_rn(x);
  float hf = __uint_as_float(((unsigned)(unsigned short)h) << 16);
  l = bf16_rn(x - hf);
}

// ---- transpose + split Wb(3072x640) -> Wth,Wtl [640][3072] bf16 -----------
__global__ __launch_bounds__(256) void split_wt(const float* __restrict__ Wb,
                                                short* __restrict__ H,
                                                short* __restrict__ L) {
  __shared__ float T[64][65];
  int n0 = blockIdx.x * 64;   // over DF
  int k0 = blockIdx.y * 64;   // over DIN
  int c = threadIdx.x & 63, r0 = threadIdx.x >> 6;
#pragma unroll
  for (int i = 0; i < 16; ++i) {
    int r = i * 4 + r0;
    T[r][c] = Wb[(size_t)(k0 + r) * DF + n0 + c];
  }
  __syncthreads();
#pragma unroll
  for (int i = 0; i < 16; ++i) {
    int n = i * 4 + r0;
    float x = T[c][n];              // Wb[k0+c][n0+n]
    short h, l; split_sh(x, h, l);
    size_t o = (size_t)(n0 + n) * DIN + k0 + c;
    H[o] = h; L[o] = l;
  }
}

// ---- MFMA GEMM via LDS staging: [S;Q](640x3072) @ Wb -> Kf, FX + K split --
// 64x64 tile, BK=64. A staged fp32 (split in-register), B staged bf16 pair.
__global__ __launch_bounds__(256) void gemm_feat(const float* __restrict__ S,
                                                 const float* __restrict__ Qm,
                                                 const short* __restrict__ Bh,
                                                 const short* __restrict__ Bl,
                                                 float* __restrict__ Kf,
                                                 float* __restrict__ FX,
                                                 short* __restrict__ Kh,
                                                 short* __restrict__ Kl) {
  __shared__ float As[64][68];    // +4 pad: stride 68 mod 32 = 4 -> 2-way max
  __shared__ short Bsh[64][72];   // +8 pad: 36 words mod 32 = 4 -> 2-way max
  __shared__ short Bsl[64][72];
  int tid = threadIdx.x;
  int wave = tid >> 6, lane = tid & 63, l16 = lane & 15, quad = lane >> 4;
  int by = blockIdx.y, bx = blockIdx.x;
  int colBase = bx * 64;
  f32x4 acc[4] = {{0,0,0,0},{0,0,0,0},{0,0,0,0},{0,0,0,0}};
  for (int k0 = 0; k0 < DIN; k0 += 64) {
    __syncthreads();
    // stage A tile: 64 rows x 64 floats, coalesced float4
#pragma unroll
    for (int p = 0; p < 4; ++p) {
      int cid = tid + 256 * p;            // 0..1023
      int row = cid >> 4, kc = cid & 15;
      int arow = by * 64 + row;
      const float* sr = (arow < MROWS) ? (S + (size_t)arow * DIN)
                                       : (Qm + (size_t)(arow - MROWS) * DIN);
      float4 v = *reinterpret_cast<const float4*>(sr + k0 + kc * 4);
      *reinterpret_cast<float4*>(&As[row][kc * 4]) = v;
    }
    // stage B tiles (both halves): 64 n-rows x 64 bf16 each
#pragma unroll
    for (int p = 0; p < 2; ++p) {
      int cid = tid + 256 * p;            // 0..511
      int nn = cid >> 3, kc = cid & 7;
      size_t src = (size_t)(colBase + nn) * DIN + k0 + kc * 8;
      *reinterpret_cast<bf8v*>(&Bsh[nn][kc * 8]) = *reinterpret_cast<const bf8v*>(Bh + src);
      *reinterpret_cast<bf8v*>(&Bsl[nn][kc * 8]) = *reinterpret_cast<const bf8v*>(Bl + src);
    }
    __syncthreads();
#pragma unroll
    for (int kk = 0; kk < 64; kk += 32) {
      int ko = kk + quad * 8;
      float4 a0 = *reinterpret_cast<const float4*>(&As[wave * 16 + l16][ko]);
      float4 a1 = *reinterpret_cast<const float4*>(&As[wave * 16 + l16][ko + 4]);
      float av[8] = {a0.x, a0.y, a0.z, a0.w, a1.x, a1.y, a1.z, a1.w};
      bf8v ah, al;
#pragma unroll
      for (int j = 0; j < 8; ++j) { short h, l; split_sh(av[j], h, l); ah[j] = h; al[j] = l; }
#pragma unroll
      for (int t = 0; t < 4; ++t) {
        bf8v bh = *reinterpret_cast<const bf8v*>(&Bsh[t * 16 + l16][ko]);
        bf8v bl = *reinterpret_cast<const bf8v*>(&Bsl[t * 16 + l16][ko]);
        acc[t] = __builtin_amdgcn_mfma_f32_16x16x32_bf16(ah, bh, acc[t], 0, 0, 0);
        acc[t] = __builtin_amdgcn_mfma_f32_16x16x32_bf16(ah, bl, acc[t], 0, 0, 0);
        acc[t] = __builtin_amdgcn_mfma_f32_16x16x32_bf16(al, bh, acc[t], 0, 0, 0);
      }
    }
  }
  int row0 = by * 64 + wave * 16;
#pragma unroll
  for (int t = 0; t < 4; ++t) {
#pragma unroll
    for (int r = 0; r < 4; ++r) {
      int row = row0 + quad * 4 + r;
      int col = colBase + t * 16 + l16;
      float v = acc[t][r];
      if (row < MROWS) {
        Kf[(size_t)row * DF + col] = v;
        short h, l; split_sh(v, h, l);
        Kh[(size_t)row * DF + col] = h;
        Kl[(size_t)row * DF + col] = l;
      } else {
        FX[(size_t)(row - MROWS) * DF + col] = v;
      }
    }
  }
}

// ---- MFMA: Apad(416x416) = K K^T + 50 I (zero-padded), fp32 out ----------
__global__ __launch_bounds__(256) void gemm_aul(const short* __restrict__ Kh,
                                                const short* __restrict__ Kl,
                                                float* __restrict__ Apad) {
  int tid = threadIdx.x;
  int wave = tid >> 6, lane = tid & 63;
  int l16 = lane & 15, quad = lane >> 4;
  int row0 = blockIdx.y * 64 + wave * 16;
  int colBase = blockIdx.x * 64;
  bool aValid = (row0 < MROWS);
  const bf8v bzero = {0,0,0,0,0,0,0,0};
  f32x4 acc[4] = {{0,0,0,0},{0,0,0,0},{0,0,0,0},{0,0,0,0}};
  for (int k0 = 0; k0 < DF; k0 += 32) {
    int ka = k0 + quad * 8;
    bf8v ah = bzero, al = bzero;
    if (aValid) {
      size_t ao = (size_t)(row0 + l16) * DF + ka;
      ah = *reinterpret_cast<const bf8v*>(Kh + ao);
      al = *reinterpret_cast<const bf8v*>(Kl + ao);
    }
#pragma unroll
    for (int t = 0; t < 4; ++t) {
      int colt = colBase + t * 16;
      bf8v bh = bzero, bl = bzero;
      if (colt < MROWS) {
        size_t bo = (size_t)(colt + l16) * DF + ka;
        bh = *reinterpret_cast<const bf8v*>(Kh + bo);
        bl = *reinterpret_cast<const bf8v*>(Kl + bo);
      }
      acc[t] = __builtin_amdgcn_mfma_f32_16x16x32_bf16(ah, bh, acc[t], 0, 0, 0);
      acc[t] = __builtin_amdgcn_mfma_f32_16x16x32_bf16(ah, bl, acc[t], 0, 0, 0);
      acc[t] = __builtin_amdgcn_mfma_f32_16x16x32_bf16(al, bh, acc[t], 0, 0, 0);
    }
  }
  if (row0 >= PN) return;
#pragma unroll
  for (int t = 0; t < 4; ++t) {
    int colt = colBase + t * 16;
    if (colt >= PN) continue;
#pragma unroll
    for (int r = 0; r < 4; ++r) {
      int row = row0 + quad * 4 + r;
      int col = colt + l16;
      float v = acc[t][r];
      if (row == col && row < MROWS) v += CREG;
      Apad[(size_t)row * PN + col] = v;
    }
  }
}

// ---- power iteration: v0 init --------------------------------------------
__global__ __launch_bounds__(256) void pv_init(float* __restrict__ V) {
  int i = blockIdx.x * 256 + threadIdx.x;
  if (i < NMAT) V[i] = 1.f + 0.125f * (float)(i & 7);
}

// ---- power iteration step: vout = (A vin) / 4096  (constant rescale) -----
__global__ __launch_bounds__(256) void pv_step(const float* __restrict__ A,
                                               const float* __restrict__ vin,
                                               float* __restrict__ vout) {
  __shared__ float Vs[NMAT];
  int tid = threadIdx.x;
  for (int e = tid; e < NMAT; e += 256) Vs[e] = vin[e];
  __syncthreads();
  int row = blockIdx.x * 256 + tid;
  if (row >= NMAT) return;
  const float* ar = A + (size_t)row * PN;
  float acc = 0.f;
  for (int j = 0; j < NMAT; j += 4) {
    float4 a4 = *reinterpret_cast<const float4*>(ar + j);
    acc += a4.x * Vs[j] + a4.y * Vs[j + 1] + a4.z * Vs[j + 2] + a4.w * Vs[j + 3];
  }
  vout[row] = acc * (1.f / 4096.f);
}

// ---- Rayleigh quotient + Chebyshev scalar schedule (Saad Alg 12.1) -------
// scal[0] = 1/theta ; scal[1+2k] = rho_{k+1}*rho_k ; scal[2+2k] = 2*rho_{k+1}/delta
__global__ __launch_bounds__(256) void pv_setup(const float* __restrict__ vprev,
                                                const float* __restrict__ vlast,
                                                float* __restrict__ scal) {
  __shared__ float rn[256], rd[256];
  int tid = threadIdx.x;
  float n = 0.f, d = 0.f;
  for (int i = tid; i < NMAT; i += 256) {
    float vp = vprev[i];
    n += vp * vlast[i];
    d += vp * vp;
  }
  rn[tid] = n; rd[tid] = d;
  __syncthreads();
  for (int o = 128; o > 0; o >>= 1) {
    if (tid < o) { rn[tid] += rn[tid + o]; rd[tid] += rd[tid + o]; }
    __syncthreads();
  }
  if (tid == 0) {
    float rq = 4096.f * rn[0] / rd[0];       // Rayleigh estimate of lambda_max
    float b = 1.3f * rq;                     // safety margin (RQ underestimates)
    if (!(b > 800.f)) b = 12000.f;           // NaN/degenerate fallback
    if (b > 100000.f) b = 100000.f;
    const float a = CREG;                    // lambda_min >= 50 provably
    float theta = 0.5f * (b + a);
    float delta = 0.5f * (b - a);
    float sigma = theta / delta;
    scal[0] = 1.f / theta;
    float rho = 1.f / sigma;
    for (int k = 0; k < NSTEPS; ++k) {
      float rho1 = 1.f / (2.f * sigma - rho);
      scal[1 + 2 * k] = rho1 * rho;
      scal[2 + 2 * k] = 2.f * rho1 / delta;
      rho = rho1;
    }
  }
}

// ---- Chebyshev init: X=0, R=P, D0 = P/theta ------------------------------
__global__ __launch_bounds__(256) void cheb_init(const float* __restrict__ scal,
                                                 float* __restrict__ X,
                                                 float* __restrict__ R,
                                                 float* __restrict__ D0) {
  int g = blockIdx.x * 256 + threadIdx.x;   // 6400
  int i = g >> 4, c = g & 15;
  float r0 = ((i / 25) == c) ? 1.f : 0.f;   // P indicator
  X[g] = 0.f;
  R[g] = r0;
  D0[g] = r0 * scal[0];
}

// ---- one Chebyshev step: x+=d; r-=A d; d = s1*d + s2*r --------------------
__global__ __launch_bounds__(256) void cheb_step(const float* __restrict__ A,
                                                 const float* __restrict__ scal,
                                                 int k,
                                                 const float* __restrict__ Din,
                                                 float* __restrict__ Dout,
                                                 float* __restrict__ X,
                                                 float* __restrict__ R) {
  __shared__ float Ds[NMAT * NRHS];   // 25.6 KB: full D, every block needs all j
  int tid = threadIdx.x;
  for (int e = tid; e < NMAT * NRHS; e += 256) Ds[e] = Din[e];
  __syncthreads();
  int g = blockIdx.x * 256 + tid;
  int i = g >> 4, c = g & 15;
  const float* ar = A + (size_t)i * PN;
  float t = 0.f;
  for (int j = 0; j < NMAT; j += 4) {
    float4 a4 = *reinterpret_cast<const float4*>(ar + j);
    t += a4.x * Ds[j * 16 + c] + a4.y * Ds[(j + 1) * 16 + c] +
         a4.z * Ds[(j + 2) * 16 + c] + a4.w * Ds[(j + 3) * 16 + c];
  }
  float dk = Ds[g];
  X[g] += dk;
  float r = R[g] - t;
  R[g] = r;
  Dout[g] = scal[1 + 2 * k] * dk + scal[2 + 2 * k] * r;
}

// ---- WK[j][d] = sum_i X[i][j] K[i][d] -------------------------------------
__global__ __launch_bounds__(256) void wk_kernel(const float* __restrict__ X,
                                                 const float* __restrict__ K,
                                                 float* __restrict__ WK) {
  int idx = blockIdx.x * 256 + threadIdx.x;
  int j = idx / DF;
  int d = idx - j * DF;
  float acc = 0.f;
  for (int i = 0; i < NMAT; ++i) acc += X[i * NRHS + j] * K[(size_t)i * DF + d];
  WK[idx] = acc;
}

// ---- logits[q][c] = -gamma * dot(FX[q], WK[c]) ----------------------------
__global__ __launch_bounds__(256) void logits_kernel(const float* __restrict__ FX,
                                                     const float* __restrict__ WK,
                                                     const float* __restrict__ gamma,
                                                     float* __restrict__ out) {
  int idx = blockIdx.x * 256 + threadIdx.x;
  int q = idx >> 4, c = idx & 15;
  const float* fr = FX + (size_t)q * DF;
  const float* wr = WK + (size_t)c * DF;
  float acc = 0.f;
  for (int d = 0; d < DF; ++d) acc += fr[d] * wr[d];
  out[idx] = -gamma[0] * acc;
}

extern "C" void kernel_launch(void* const* d_in, const int* in_sizes, int n_in,
                              void* d_out, int out_size, void* d_ws, size_t ws_size,
                              hipStream_t stream) {
  const float* S = (const float*)d_in[0];
  const float* Qm = (const float*)d_in[1];
  const float* Wb = (const float*)d_in[2];
  const float* gamma = (const float*)d_in[3];
  float* out = (float*)d_out;
  char* base = (char*)d_ws;
  // persistent (~2.9 MB)
  float* Kf  = (float*)(base);                 // 400*640*4 = 1,024,000
  float* FX  = (float*)(base + 1024000);       // 240*640*4 =   614,400
  short* Kh  = (short*)(base + 1638400);       // 512,000
  short* Kl  = (short*)(base + 2150400);       // 512,000
  float* WK  = (float*)(base + 2662400);       // 40,960
  float* Xb  = (float*)(base + 2703360);       // 25,600
  float* Rb  = (float*)(base + 2728960);       // 25,600
  float* D0  = (float*)(base + 2754560);       // 25,600
  float* D1  = (float*)(base + 2780160);       // 25,600
  float* V0  = (float*)(base + 2805760);       // 1,664
  float* V1  = (float*)(base + 2807424);       // 1,664
  float* scal= (float*)(base + 2809088);       // 65*4
  char* big = base + 2809600;
  // phase 1: Wb transposed splits; phase 2 Apad aliases (Wth dead by then)
  short* Wth = (short*)(big);                  // 640*3072*2 = 3,932,160
  short* Wtl = (short*)(big + 3932160);        // 3,932,160
  float* Apad= (float*)(big + 7864320);        // 416*416*4 = 692,224 (total ~11.4 MB)

  split_wt<<<dim3(10, 48), 256, 0, stream>>>(Wb, Wth, Wtl);
  gemm_feat<<<dim3(10, 10), 256, 0, stream>>>(S, Qm, Wth, Wtl, Kf, FX, Kh, Kl);
  gemm_aul<<<dim3(7, 7), 256, 0, stream>>>(Kh, Kl, Apad);
  // --- spectral bound via power iteration (tight lambda_max -> fewer steps)
  pv_init<<<2, 256, 0, stream>>>(V0);
  {
    float* a = V0; float* b = V1;
    for (int it = 0; it < PVSTEPS; ++it) {
      pv_step<<<2, 256, 0, stream>>>(Apad, a, b);
      float* t = a; a = b; b = t;
    }
    // after 8 steps: last out = V0 (a), prev = V1 (b)
    pv_setup<<<1, 256, 0, stream>>>(b, a, scal);
  }
  // --- Chebyshev semi-iteration on A X = P (no reductions, 1 launch/step)
  cheb_init<<<25, 256, 0, stream>>>(scal, Xb, Rb, D0);
  {
    float* din = D0; float* dout = D1;
    for (int k = 0; k < NSTEPS; ++k) {
      cheb_step<<<25, 256, 0, stream>>>(Apad, scal, k, din, dout, Xb, Rb);
      float* t = din; din = dout; dout = t;
    }
  }
  wk_kernel<<<40, 256, 0, stream>>>(Xb, Kf, WK);
  logits_kernel<<<15, 256, 0, stream>>>(FX, WK, gamma, out);
}

// Round 5
// 439.893 us; speedup vs baseline: 4.2365x; 1.4132x over previous
//
#include <hip/hip_runtime.h>
#include <math.h>

#define DIN 3072
#define DF 640
#define MROWS 400
#define QROWS 240
#define NMAT 400
#define PN 416          // padded A dim (13*32)
#define NRHS 16
#define CREG 50.0f
#define PVSTEPS 8
#define CSTEPS 28       // Chebyshev steps: rate~0.78 -> rel ~1.9e-3
#define NBLK 25         // solve_fused grid (must divide 400/16)
#define KSPLIT 8        // gemm_feat split-K factor

typedef __attribute__((ext_vector_type(8))) short bf8v;   // 8 bf16 (4 VGPRs)
typedef __attribute__((ext_vector_type(4))) float f32x4;  // MFMA acc

__device__ __forceinline__ short bf16_rn(float x) {
  unsigned u = __float_as_uint(x);
  u += 0x7FFFu + ((u >> 16) & 1u);
  return (short)(u >> 16);
}
__device__ __forceinline__ void split_sh(float x, short& h, short& l) {
  h = bf16_rn(x);
  float hf = __uint_as_float(((unsigned)(unsigned short)h) << 16);
  l = bf16_rn(x - hf);
}
__device__ __forceinline__ float bf2f(short h) {
  return __uint_as_float(((unsigned)(unsigned short)h) << 16);
}

// ---- transpose + split Wb(3072x640) -> Wth,Wtl [640][3072] bf16 -----------
__global__ __launch_bounds__(256) void split_wt(const float* __restrict__ Wb,
                                                short* __restrict__ H,
                                                short* __restrict__ L) {
  __shared__ float T[64][65];
  int n0 = blockIdx.x * 64;   // over DF
  int k0 = blockIdx.y * 64;   // over DIN
  int c = threadIdx.x & 63, r0 = threadIdx.x >> 6;
#pragma unroll
  for (int i = 0; i < 16; ++i) {
    int r = i * 4 + r0;
    T[r][c] = Wb[(size_t)(k0 + r) * DF + n0 + c];
  }
  __syncthreads();
#pragma unroll
  for (int i = 0; i < 16; ++i) {
    int n = i * 4 + r0;
    float x = T[c][n];              // Wb[k0+c][n0+n]
    short h, l; split_sh(x, h, l);
    size_t o = (size_t)(n0 + n) * DIN + k0 + c;
    H[o] = h; L[o] = l;
  }
}

// ---- split-K MFMA GEMM: partial [S;Q] @ Wb -> atomicAdd into Acc(640x640) -
__global__ __launch_bounds__(256) void gemm_feat_sk(const float* __restrict__ S,
                                                    const float* __restrict__ Qm,
                                                    const short* __restrict__ Bh,
                                                    const short* __restrict__ Bl,
                                                    float* __restrict__ Acc) {
  __shared__ float As[64][68];
  __shared__ short Bsh[64][72];
  __shared__ short Bsl[64][72];
  int tid = threadIdx.x;
  int wave = tid >> 6, lane = tid & 63, l16 = lane & 15, quad = lane >> 4;
  int by = blockIdx.y, bx = blockIdx.x, bz = blockIdx.z;
  int colBase = bx * 64;
  int kbeg = bz * (DIN / KSPLIT), kend = kbeg + (DIN / KSPLIT);
  f32x4 acc[4] = {{0,0,0,0},{0,0,0,0},{0,0,0,0},{0,0,0,0}};
  for (int k0 = kbeg; k0 < kend; k0 += 64) {
    __syncthreads();
#pragma unroll
    for (int p = 0; p < 4; ++p) {
      int cid = tid + 256 * p;            // 0..1023
      int row = cid >> 4, kc = cid & 15;
      int arow = by * 64 + row;
      const float* sr = (arow < MROWS) ? (S + (size_t)arow * DIN)
                                       : (Qm + (size_t)(arow - MROWS) * DIN);
      float4 v = *reinterpret_cast<const float4*>(sr + k0 + kc * 4);
      *reinterpret_cast<float4*>(&As[row][kc * 4]) = v;
    }
#pragma unroll
    for (int p = 0; p < 2; ++p) {
      int cid = tid + 256 * p;            // 0..511
      int nn = cid >> 3, kc = cid & 7;
      size_t src = (size_t)(colBase + nn) * DIN + k0 + kc * 8;
      *reinterpret_cast<bf8v*>(&Bsh[nn][kc * 8]) = *reinterpret_cast<const bf8v*>(Bh + src);
      *reinterpret_cast<bf8v*>(&Bsl[nn][kc * 8]) = *reinterpret_cast<const bf8v*>(Bl + src);
    }
    __syncthreads();
#pragma unroll
    for (int kk = 0; kk < 64; kk += 32) {
      int ko = kk + quad * 8;
      float4 a0 = *reinterpret_cast<const float4*>(&As[wave * 16 + l16][ko]);
      float4 a1 = *reinterpret_cast<const float4*>(&As[wave * 16 + l16][ko + 4]);
      float av[8] = {a0.x, a0.y, a0.z, a0.w, a1.x, a1.y, a1.z, a1.w};
      bf8v ah, al;
#pragma unroll
      for (int j = 0; j < 8; ++j) { short h, l; split_sh(av[j], h, l); ah[j] = h; al[j] = l; }
#pragma unroll
      for (int t = 0; t < 4; ++t) {
        bf8v bh = *reinterpret_cast<const bf8v*>(&Bsh[t * 16 + l16][ko]);
        bf8v bl = *reinterpret_cast<const bf8v*>(&Bsl[t * 16 + l16][ko]);
        acc[t] = __builtin_amdgcn_mfma_f32_16x16x32_bf16(ah, bh, acc[t], 0, 0, 0);
        acc[t] = __builtin_amdgcn_mfma_f32_16x16x32_bf16(ah, bl, acc[t], 0, 0, 0);
        acc[t] = __builtin_amdgcn_mfma_f32_16x16x32_bf16(al, bh, acc[t], 0, 0, 0);
      }
    }
  }
  int row0 = by * 64 + wave * 16;
#pragma unroll
  for (int t = 0; t < 4; ++t) {
#pragma unroll
    for (int r = 0; r < 4; ++r) {
      int row = row0 + quad * 4 + r;
      int col = colBase + t * 16 + l16;
      atomicAdd(&Acc[(size_t)row * DF + col], acc[t][r]);
    }
  }
}

// ---- finalize: Acc -> Kh,Kl (rows<400) / FX (rows>=400) -------------------
__global__ __launch_bounds__(256) void finalize_feat(const float* __restrict__ Acc,
                                                     short* __restrict__ Kh,
                                                     short* __restrict__ Kl,
                                                     float* __restrict__ FX) {
  int idx = blockIdx.x * 256 + threadIdx.x;   // < 640*640
  if (idx >= 640 * DF) return;
  float v = Acc[idx];
  int row = idx / DF, col = idx - row * DF;
  if (row < MROWS) {
    short h, l; split_sh(v, h, l);
    Kh[(size_t)row * DF + col] = h;
    Kl[(size_t)row * DF + col] = l;
  } else {
    FX[(size_t)(row - MROWS) * DF + col] = v;
  }
}

// ---- MFMA: Apad(416x416) = K K^T + 50 I (zero-padded), fp32 out -----------
__global__ __launch_bounds__(256) void gemm_aul(const short* __restrict__ Kh,
                                                const short* __restrict__ Kl,
                                                float* __restrict__ Apad) {
  int tid = threadIdx.x;
  int wave = tid >> 6, lane = tid & 63;
  int l16 = lane & 15, quad = lane >> 4;
  int row0 = blockIdx.y * 64 + wave * 16;
  int colBase = blockIdx.x * 64;
  bool aValid = (row0 < MROWS);
  const bf8v bzero = {0,0,0,0,0,0,0,0};
  f32x4 acc[4] = {{0,0,0,0},{0,0,0,0},{0,0,0,0},{0,0,0,0}};
  for (int k0 = 0; k0 < DF; k0 += 32) {
    int ka = k0 + quad * 8;
    bf8v ah = bzero, al = bzero;
    if (aValid) {
      size_t ao = (size_t)(row0 + l16) * DF + ka;
      ah = *reinterpret_cast<const bf8v*>(Kh + ao);
      al = *reinterpret_cast<const bf8v*>(Kl + ao);
    }
#pragma unroll
    for (int t = 0; t < 4; ++t) {
      int colt = colBase + t * 16;
      bf8v bh = bzero, bl = bzero;
      if (colt < MROWS) {
        size_t bo = (size_t)(colt + l16) * DF + ka;
        bh = *reinterpret_cast<const bf8v*>(Kh + bo);
        bl = *reinterpret_cast<const bf8v*>(Kl + bo);
      }
      acc[t] = __builtin_amdgcn_mfma_f32_16x16x32_bf16(ah, bh, acc[t], 0, 0, 0);
      acc[t] = __builtin_amdgcn_mfma_f32_16x16x32_bf16(ah, bl, acc[t], 0, 0, 0);
      acc[t] = __builtin_amdgcn_mfma_f32_16x16x32_bf16(al, bh, acc[t], 0, 0, 0);
    }
  }
  if (row0 >= PN) return;
#pragma unroll
  for (int t = 0; t < 4; ++t) {
    int colt = colBase + t * 16;
    if (colt >= PN) continue;
#pragma unroll
    for (int r = 0; r < 4; ++r) {
      int row = row0 + quad * 4 + r;
      int col = colt + l16;
      float v = acc[t][r];
      if (row == col && row < MROWS) v += CREG;
      Apad[(size_t)row * PN + col] = v;
    }
  }
}

// ---- fused solve: power-iter (lambda_max) + Chebyshev on A X = P ----------
// 25 blocks x 256 thr; block b owns rows b*16..b*16+15; thread=(row r, rhs c).
// Grid barrier: monotonic device-scope atomic counter; 25 blocks << 256 CUs
// guarantees co-residency; __threadfence() = agent fence handles XCD L2s.
__global__ __launch_bounds__(256) void solve_fused(const float* __restrict__ A,
                                                   float* __restrict__ V0,
                                                   float* __restrict__ V1,
                                                   float* __restrict__ D0,
                                                   float* __restrict__ D1,
                                                   float* __restrict__ rq,
                                                   unsigned* __restrict__ bar,
                                                   float* __restrict__ X) {
  __shared__ float sh[NMAT];
  __shared__ float part[16][17];
  __shared__ float Ds[NMAT * NRHS];   // 25.6 KB
  int tid = threadIdx.x, b = blockIdx.x;
  int r = tid >> 4, c = tid & 15;
  int i = b * 16 + r;                  // global row 0..399
  unsigned ph = 0;
  auto gridbar = [&]() {
    __syncthreads();
    ++ph;                              // uniform across all threads
    if (tid == 0) {
      __threadfence();
      atomicAdd(bar, 1u);
      unsigned tgt = ph * NBLK;
      while (atomicAdd(bar, 0u) < tgt) __builtin_amdgcn_s_sleep(2);
      __threadfence();
    }
    __syncthreads();
  };

  // ---- power iteration for lambda_max ----
  if (c == 0) V0[i] = 1.f + 0.125f * (float)(i & 7);
  gridbar();
  float* vc = V0; float* vn = V1;
  for (int s = 0; s < PVSTEPS; ++s) {
    for (int e = tid; e < NMAT; e += 256) sh[e] = vc[e];
    __syncthreads();
    const float* ar = A + (size_t)i * PN + c * 25;
    float p = 0.f;
#pragma unroll
    for (int u = 0; u < 25; ++u) p += ar[u] * sh[c * 25 + u];
    part[r][c] = p;
    __syncthreads();
    if (c == 0) {
      float s2 = 0.f;
#pragma unroll
      for (int q = 0; q < 16; ++q) s2 += part[r][q];
      vn[i] = s2 * (1.f / 4096.f);
    }
    gridbar();
    float* t = vc; vc = vn; vn = t;    // vc = latest, vn = previous
  }
  // ---- Rayleigh quotient -> Chebyshev interval ----
  if (c == 0) { float vp = vn[i]; part[r][0] = vp * vc[i]; part[r][1] = vp * vp; }
  __syncthreads();
  if (tid == 0) {
    float sn = 0.f, sd = 0.f;
    for (int q = 0; q < 16; ++q) { sn += part[q][0]; sd += part[q][1]; }
    atomicAdd(&rq[0], sn);
    atomicAdd(&rq[1], sd);
  }
  gridbar();
  float rqv = 4096.f * rq[0] / rq[1];
  float bnd = 1.3f * rqv;
  if (!(bnd > 800.f)) bnd = 12000.f;   // NaN/degenerate fallback
  if (bnd > 100000.f) bnd = 100000.f;
  const float aa = CREG;               // lambda_min >= 50 provable
  float theta = 0.5f * (bnd + aa), delta = 0.5f * (bnd - aa);
  float sigma = theta / delta;
  float rho = 1.f / sigma;
  // ---- Chebyshev semi-iteration (Saad Alg 12.1); x,r in registers ----
  float pc = ((i / 25) == c) ? 1.f : 0.f;
  float x = 0.f, rr = pc;
  D0[i * NRHS + c] = pc / theta;
  gridbar();
  float* dc = D0; float* dn = D1;
  for (int k = 0; k < CSTEPS; ++k) {
    for (int e = tid; e < NMAT * NRHS; e += 256) Ds[e] = dc[e];
    __syncthreads();
    const float* ar = A + (size_t)i * PN;
    float mv = 0.f;
    for (int j = 0; j < NMAT; j += 4) {
      float4 a4 = *reinterpret_cast<const float4*>(ar + j);
      mv += a4.x * Ds[j * 16 + c] + a4.y * Ds[(j + 1) * 16 + c] +
            a4.z * Ds[(j + 2) * 16 + c] + a4.w * Ds[(j + 3) * 16 + c];
    }
    float dk = Ds[i * 16 + c];
    x += dk;
    rr -= mv;
    float rho1 = 1.f / (2.f * sigma - rho);
    float s1 = rho1 * rho, s2 = 2.f * rho1 / delta;
    rho = rho1;
    dn[i * NRHS + c] = s1 * dk + s2 * rr;
    gridbar();
    float* t = dc; dc = dn; dn = t;
  }
  X[i * NRHS + c] = x;
}

// ---- WK[j][d] = sum_i X[i][j] K[i][d], K = Kh+Kl --------------------------
__global__ __launch_bounds__(256) void wk_kernel(const float* __restrict__ X,
                                                 const short* __restrict__ Kh,
                                                 const short* __restrict__ Kl,
                                                 float* __restrict__ WK) {
  int idx = blockIdx.x * 256 + threadIdx.x;   // < 16*640
  int j = idx / DF;
  int d = idx - j * DF;
  float acc = 0.f;
  for (int i = 0; i < NMAT; ++i) {
    float kv = bf2f(Kh[(size_t)i * DF + d]) + bf2f(Kl[(size_t)i * DF + d]);
    acc += X[i * NRHS + j] * kv;
  }
  WK[idx] = acc;
}

// ---- logits[q][c] = -gamma * dot(FX[q], WK[c]) ----------------------------
__global__ __launch_bounds__(256) void logits_kernel(const float* __restrict__ FX,
                                                     const float* __restrict__ WK,
                                                     const float* __restrict__ gamma,
                                                     float* __restrict__ out) {
  int idx = blockIdx.x * 256 + threadIdx.x;
  int q = idx >> 4, c = idx & 15;
  const float* fr = FX + (size_t)q * DF;
  const float* wr = WK + (size_t)c * DF;
  float acc = 0.f;
  for (int d = 0; d < DF; ++d) acc += fr[d] * wr[d];
  out[idx] = -gamma[0] * acc;
}

extern "C" void kernel_launch(void* const* d_in, const int* in_sizes, int n_in,
                              void* d_out, int out_size, void* d_ws, size_t ws_size,
                              hipStream_t stream) {
  const float* S = (const float*)d_in[0];
  const float* Qm = (const float*)d_in[1];
  const float* Wb = (const float*)d_in[2];
  const float* gamma = (const float*)d_in[3];
  float* out = (float*)d_out;
  char* base = (char*)d_ws;
  // persistent region
  float* FX   = (float*)(base);                 // 240*640*4 = 614,400
  short* Kh   = (short*)(base + 614400);        // 512,000
  short* Kl   = (short*)(base + 1126400);       // 512,000
  float* WK   = (float*)(base + 1638400);       // 40,960
  float* Xb   = (float*)(base + 1679360);       // 25,600
  char*  ctrl = base + 1704960;                 // 64 B: rq[2], bar
  float* rq   = (float*)ctrl;
  unsigned* bar = (unsigned*)(ctrl + 32);
  float* Acc  = (float*)(base + 1705024);       // 640*640*4 = 1,638,400
  // Wt region: live only until gemm_feat_sk; solve buffers alias it after
  char* wt = base + 3343424;
  short* Wth = (short*)(wt);                    // 640*3072*2 = 3,932,160
  short* Wtl = (short*)(wt + 3932160);          // 3,932,160  -> end 11,207,744
  float* Apad = (float*)(wt);                   // 692,224 (aliases dead Wth)
  float* D0   = (float*)(wt + 692224);          // 25,600
  float* D1   = (float*)(wt + 717824);          // 25,600
  float* V0   = (float*)(wt + 743424);          // 1,664
  float* V1   = (float*)(wt + 745088);          // 1,664

  // zero ctrl + Acc in one shot (adjacent)
  hipMemsetAsync(ctrl, 0, 64 + 1638400, stream);
  split_wt<<<dim3(10, 48), 256, 0, stream>>>(Wb, Wth, Wtl);
  gemm_feat_sk<<<dim3(10, 10, KSPLIT), 256, 0, stream>>>(S, Qm, Wth, Wtl, Acc);
  finalize_feat<<<1600, 256, 0, stream>>>(Acc, Kh, Kl, FX);
  gemm_aul<<<dim3(7, 7), 256, 0, stream>>>(Kh, Kl, Apad);
  solve_fused<<<NBLK, 256, 0, stream>>>(Apad, V0, V1, D0, D1, rq, bar, Xb);
  wk_kernel<<<40, 256, 0, stream>>>(Xb, Kh, Kl, WK);
  logits_kernel<<<15, 256, 0, stream>>>(FX, WK, gamma, out);
}